// Round 1
// baseline (320.948 us; speedup 1.0000x reference)
//
#include <hip/hip_runtime.h>
#include <math.h>

#define BB 16
#define NN 2048
#define DD 1024
#define KH 15
#define KL 5
#define NH 240      // BB*KH
#define NBANK 320   // BB*(KH+KL)

// ws layout (4-byte words):
//  [0] gmax  [1] gmin  [2] sum(score)
//  word 16 : selH[240] (int, -1 = invalid)
//  word 256: selL[80]  (int, -1 = invalid)
//  word 336: perq[320] (float)

__global__ void k_stats(const float* __restrict__ score, float* ws) {
    __shared__ float smax[256], smin[256], ssum[256];
    int t = threadIdx.x;
    float mx = -1e30f, mn = 1e30f, sm = 0.f;
    for (int i = t; i < BB * NN; i += 256) {
        float s = score[i];
        mx = fmaxf(mx, s); mn = fminf(mn, s); sm += s;
    }
    smax[t] = mx; smin[t] = mn; ssum[t] = sm;
    __syncthreads();
    for (int s2 = 128; s2 > 0; s2 >>= 1) {
        if (t < s2) {
            smax[t] = fmaxf(smax[t], smax[t + s2]);
            smin[t] = fminf(smin[t], smin[t + s2]);
            ssum[t] += ssum[t + s2];
        }
        __syncthreads();
    }
    if (t == 0) { ws[0] = smax[0]; ws[1] = smin[0]; ws[2] = ssum[0]; }
}

// one block per bag; iterative lexicographic-min selection
__global__ void k_select(const float* __restrict__ score, const float* __restrict__ ws,
                         int* __restrict__ selH, int* __restrict__ selL) {
    const unsigned long long INVALID = ~0ULL;
    int b = blockIdx.x, t = threadIdx.x;
    float gmax = ws[0], gmin = ws[1];
    float hlo = gmax - 0.3f;
    float llo = gmin, lhi = gmin + 1e-9f;
    const float* sc = score + b * NN;

    // cache (score_bits, idx) keys; scores in [0,1) so bit order == value order
    unsigned long long keys[NN / 256];
    for (int j = 0; j < NN / 256; ++j) {
        int i = t + j * 256;
        unsigned int bits = __float_as_uint(sc[i]);
        keys[j] = ((unsigned long long)bits << 32) | (unsigned int)i;
    }

    __shared__ unsigned long long red[256];

    // ---- H: first 15 (ascending score, then idx) with score >= gmax-0.3 ----
    unsigned long long prev = 0; bool first = true;
    for (int k = 0; k < KH; ++k) {
        unsigned long long best = INVALID;
        for (int j = 0; j < NN / 256; ++j) {
            unsigned long long key = keys[j];
            float s = __uint_as_float((unsigned int)(key >> 32));
            if (s >= hlo && (first || key > prev) && key < best) best = key;
        }
        red[t] = best; __syncthreads();
        for (int s2 = 128; s2 > 0; s2 >>= 1) {
            if (t < s2) { if (red[t + s2] < red[t]) red[t] = red[t + s2]; }
            __syncthreads();
        }
        unsigned long long w = red[0];
        __syncthreads();
        if (w == INVALID) {
            if (t == 0) for (int kk = k; kk < KH; ++kk) selH[b * KH + kk] = -1;
            break;
        }
        if (t == 0) selH[b * KH + k] = (int)(w & 0xffffffffu);
        prev = w; first = false;
    }

    // ---- L: even-rank elements (ranks 0,2,..,8) in [gmin, gmin+1e-9] ----
    prev = 0; first = true;
    int nsel = 0;
    for (int r = 0; r < 2 * KL; ++r) {
        unsigned long long best = INVALID;
        for (int j = 0; j < NN / 256; ++j) {
            unsigned long long key = keys[j];
            float s = __uint_as_float((unsigned int)(key >> 32));
            if (s >= llo && s <= lhi && (first || key > prev) && key < best) best = key;
        }
        red[t] = best; __syncthreads();
        for (int s2 = 128; s2 > 0; s2 >>= 1) {
            if (t < s2) { if (red[t + s2] < red[t]) red[t] = red[t + s2]; }
            __syncthreads();
        }
        unsigned long long w = red[0];
        __syncthreads();
        if (w == INVALID) break;
        if ((r & 1) == 0) {
            if (t == 0) selL[b * KL + (r >> 1)] = (int)(w & 0xffffffffu);
            nsel++;
        }
        prev = w; first = false;
    }
    if (t == 0) for (int kk = nsel; kk < KL; ++kk) selL[b * KL + kk] = -1;
}

// one block per query row q (== bank row q); 320 threads, one per bank column
__global__ void __launch_bounds__(320)
k_gram(const float* __restrict__ fea, const int* __restrict__ selH,
       const int* __restrict__ selL, const int* __restrict__ label,
       float* __restrict__ perq) {
    int q = blockIdx.x, t = threadIdx.x;
    int bq, iq, qt;
    if (q < NH) { bq = q / KH; iq = selH[q]; qt = label[bq]; }
    else        { bq = (q - NH) / KL; iq = selL[q - NH]; qt = 2; }
    if (iq < 0) { if (t == 0) perq[q] = 0.f; return; }

    __shared__ __align__(16) float qrow[DD];
    const float* qsrc = fea + ((size_t)bq * NN + iq) * DD;
    for (int i = t; i < DD; i += 320) qrow[i] = qsrc[i];
    __syncthreads();

    int n = t;
    int bn, in_, ln;
    if (n < NH) { bn = n / KH; in_ = selH[n]; ln = label[bn]; }
    else        { bn = (n - NH) / KL; in_ = selL[n - NH]; ln = 2; }

    double e = 0.0;
    if (in_ >= 0) {
        const float4* crow = (const float4*)(fea + ((size_t)bn * NN + in_) * DD);
        const float4* qr4 = (const float4*)qrow;
        float acc = 0.f;
        for (int i = 0; i < DD / 4; ++i) {
            float4 c = crow[i]; float4 v = qr4[i];
            acc += c.x * v.x + c.y * v.y + c.z * v.z + c.w * v.w;
        }
        e = exp((double)acc / 16.0);
    }

    __shared__ double rden[NBANK], rnum[NBANK];
    rden[t] = e;
    rnum[t] = (ln == qt) ? e : 0.0;
    __syncthreads();
    if (t < 64) { rden[t] += rden[t + 256]; rnum[t] += rnum[t + 256]; }
    __syncthreads();
    if (t < 128) { rden[t] += rden[t + 128]; rnum[t] += rnum[t + 128]; }
    __syncthreads();
    if (t < 64) { rden[t] += rden[t + 64]; rnum[t] += rnum[t + 64]; }
    __syncthreads();
    if (t == 0) {
        double den = 0.0, num = 0.0;
        for (int i = 0; i < 64; ++i) { den += rden[i]; num += rnum[i]; }
        perq[q] = (float)(-(log(num) - log(den)));
    }
}

__global__ void k_final(const float* __restrict__ perq, const int* __restrict__ selH,
                        const int* __restrict__ selL, const float* __restrict__ t_logit,
                        const float* __restrict__ ori, const float* __restrict__ l2_wei,
                        const float* __restrict__ ws, float* __restrict__ out) {
    if (threadIdx.x != 0 || blockIdx.x != 0) return;
    float contrast = 0.f;
    for (int b = 0; b < BB; ++b) {
        float s = 0.f; int cnt = 0;
        for (int k = 0; k < KH; ++k) {
            int q = b * KH + k;
            if (selH[q] >= 0) { s += perq[q]; cnt++; }
        }
        for (int k = 0; k < KL; ++k) {
            int q = b * KL + k;
            if (selL[q] >= 0) { s += perq[NH + q]; cnt++; }
        }
        contrast += s / (float)cnt;
    }
    contrast /= (float)BB;
    float tl = t_logit[0];
    float ce = 0.f;
    for (int b = 0; b < BB; ++b) {
        float d = expf(ori[b * 2 + 0]) + expf(ori[b * 2 + 1]);
        ce += logf(d) - tl;
    }
    ce /= (float)BB;
    float gmax = ws[0];
    float mean = ws[2] / (float)(BB * NN);
    float Dm = mean / gmax;
    float l2 = 0.0001f * (1.f - Dm) * (1.f - Dm) * l2_wei[0];
    out[0] = contrast + ce + l2;
}

extern "C" void kernel_launch(void* const* d_in, const int* in_sizes, int n_in,
                              void* d_out, int out_size, void* d_ws, size_t ws_size,
                              hipStream_t stream) {
    const float* fea    = (const float*)d_in[0];
    const float* score  = (const float*)d_in[1];
    const int*   label  = (const int*)d_in[2];
    const float* t_logit= (const float*)d_in[3];
    const float* ori    = (const float*)d_in[4];
    const float* l2_wei = (const float*)d_in[5];
    float* ws = (float*)d_ws;
    int* selH = (int*)d_ws + 16;
    int* selL = (int*)d_ws + 256;
    float* perq = ws + 336;
    float* out = (float*)d_out;

    hipLaunchKernelGGL(k_stats,  dim3(1),     dim3(256), 0, stream, score, ws);
    hipLaunchKernelGGL(k_select, dim3(BB),    dim3(256), 0, stream, score, ws, selH, selL);
    hipLaunchKernelGGL(k_gram,   dim3(NBANK), dim3(320), 0, stream, fea, selH, selL, label, perq);
    hipLaunchKernelGGL(k_final,  dim3(1),     dim3(64),  0, stream, perq, selH, selL, t_logit, ori, l2_wei, ws, out);
}